// Round 1
// baseline (126.029 us; speedup 1.0000x reference)
//
#include <hip/hip_runtime.h>
#include <math.h>

// Problem constants
#define BB 4096      // batch
#define DD 512       // feature dim
#define CC 1000      // num classes
#define CPAD 1024    // padded classes
#define AM 16        // anchors per center-block

// ---------------- ws layout (floats) ----------------
// ETp      : [128][1024][4]  = 524288
// esq      : 1024
// asq      : 4096
// ce_part  : 3072
// ctr_part : 256
// tr_part  : 1024
#define OFF_ETP  0
#define OFF_ESQ  524288
#define OFF_ASQ  525312
#define OFF_CEP  529408
#define OFF_CTP  532480
#define OFF_TRP  532736

// Pack exemplars^T: ETp[d4][c][0..3] = E[c][4*d4 + 0..3], zero-padded c>=1000
__global__ void transpose_kernel(const float* __restrict__ ex, float* __restrict__ ETp) {
    int t = blockIdx.x * 256 + threadIdx.x;     // 0 .. 131071
    int d4 = t >> 10, c = t & 1023;
    float4 v = make_float4(0.f, 0.f, 0.f, 0.f);
    if (c < CC) v = *(const float4*)(ex + (size_t)c * DD + d4 * 4);
    *(float4*)(ETp + ((size_t)(d4 * CPAD + c)) * 4) = v;
}

// esq[c] = sum_d E[c][d]^2  (0 for padded classes)
__global__ void esq_kernel(const float* __restrict__ ex, float* __restrict__ esq) {
    int wid = threadIdx.x >> 6, lane = threadIdx.x & 63;
    int c = blockIdx.x * 4 + wid;               // grid 256 -> c in [0,1024)
    float s = 0.f;
    if (c < CC) {
        const float4* row = (const float4*)(ex + (size_t)c * DD);
#pragma unroll
        for (int k = 0; k < 2; k++) {
            float4 v = row[lane + k * 64];
            s += v.x * v.x + v.y * v.y + v.z * v.z + v.w * v.w;
        }
        for (int off = 32; off; off >>= 1) s += __shfl_xor(s, off);
    }
    if (lane == 0) esq[c] = s;
}

// Cross-entropy: one wave per row of outputs [12288][1000]; block partial sums.
__global__ void ce_kernel(const float* __restrict__ outp,
                          const int* __restrict__ la, const int* __restrict__ ln,
                          float* __restrict__ part) {
    int wid = threadIdx.x >> 6, lane = threadIdx.x & 63;
    int r = blockIdx.x * 4 + wid;               // grid 3072 -> r in [0,12288)
    int label = (r < 2 * BB) ? la[r & (BB - 1)] : ln[r - 2 * BB];
    const float* row = outp + (size_t)r * CC;
    float v[16];
#pragma unroll
    for (int k = 0; k < 16; k++) {
        int j = lane + k * 64;
        v[k] = (j < CC) ? row[j] : -INFINITY;
    }
    float m = v[0];
#pragma unroll
    for (int k = 1; k < 16; k++) m = fmaxf(m, v[k]);
    for (int off = 32; off; off >>= 1) m = fmaxf(m, __shfl_xor(m, off));
    float s = 0.f, lv = 0.f;
#pragma unroll
    for (int k = 0; k < 16; k++) {
        int j = lane + k * 64;
        s += __expf(v[k] - m);
        lv += (j == label) ? v[k] : 0.f;
    }
    for (int off = 32; off; off >>= 1) {
        s += __shfl_xor(s, off);
        lv += __shfl_xor(lv, off);
    }
    __shared__ float ps[4];
    if (lane == 0) ps[wid] = -(lv - m - __logf(s));
    __syncthreads();
    if (threadIdx.x == 0) part[blockIdx.x] = ps[0] + ps[1] + ps[2] + ps[3];
}

// Triplet loss per row + anchor squared norms. One wave per row.
__global__ void triplet_kernel(const float* __restrict__ a, const float* __restrict__ p,
                               const float* __restrict__ n, float* __restrict__ part,
                               float* __restrict__ asq) {
    int wid = threadIdx.x >> 6, lane = threadIdx.x & 63;
    int i = blockIdx.x * 4 + wid;               // grid 1024 -> i in [0,4096)
    const float4* ar = (const float4*)(a + (size_t)i * DD);
    const float4* pr = (const float4*)(p + (size_t)i * DD);
    const float4* nr = (const float4*)(n + (size_t)i * DD);
    float sa = 0.f, sp = 0.f, sn = 0.f;
#pragma unroll
    for (int k = 0; k < 2; k++) {
        int j = lane + k * 64;
        float4 av = ar[j], pv = pr[j], nv = nr[j];
        sa += av.x * av.x + av.y * av.y + av.z * av.z + av.w * av.w;
        float dx = av.x - pv.x, dy = av.y - pv.y, dz = av.z - pv.z, dw = av.w - pv.w;
        sp += dx * dx + dy * dy + dz * dz + dw * dw;
        dx = av.x - nv.x; dy = av.y - nv.y; dz = av.z - nv.z; dw = av.w - nv.w;
        sn += dx * dx + dy * dy + dz * dz + dw * dw;
    }
    for (int off = 32; off; off >>= 1) {
        sa += __shfl_xor(sa, off);
        sp += __shfl_xor(sp, off);
        sn += __shfl_xor(sn, off);
    }
    __shared__ float ps[4];
    if (lane == 0) {
        asq[i] = sa;
        ps[wid] = fmaxf(sqrtf(sp) - sqrtf(sn), 0.f);
    }
    __syncthreads();
    if (threadIdx.x == 0) part[blockIdx.x] = ps[0] + ps[1] + ps[2] + ps[3];
}

// Center loss: block = 1024 threads, thread owns class c = tid (padded to 1024).
// Block handles AM=16 anchors; anchor data via wave-uniform (scalar) loads.
__global__ __launch_bounds__(1024) void center_kernel(
    const float* __restrict__ ETp, const float* __restrict__ anchor,
    const float* __restrict__ asq, const float* __restrict__ esq,
    const int* __restrict__ la, float* __restrict__ out_part)
{
    int tid = threadIdx.x;
    int c = tid;                                // class 0..1023
    int a0 = blockIdx.x * AM;

    float acc[AM];
#pragma unroll
    for (int a = 0; a < AM; a++) acc[a] = 0.f;

    for (int d4 = 0; d4 < DD / 4; d4++) {
        const float4 e = *(const float4*)(ETp + ((size_t)(d4 * CPAD + c)) * 4);
#pragma unroll
        for (int a = 0; a < AM; a++) {
            // uniform address -> scalar load path
            const float4 av = *(const float4*)(anchor + (size_t)(a0 + a) * DD + d4 * 4);
            acc[a] += av.x * e.x + av.y * e.y + av.z * e.z + av.w * e.w;
        }
    }

    int valid = (c < CC);
    float myesq = esq[c];
    float vals[AM];
#pragma unroll
    for (int a = 0; a < AM; a++) {
        float d2 = asq[a0 + a] + myesq - 2.f * acc[a];
        float dd = sqrtf(fmaxf(d2, 0.f));
        vals[a] = valid ? dd : INFINITY;
    }

    __shared__ float s_min[16][AM];
    __shared__ float s_ref[16][AM];
    int wid = tid >> 6, lane = tid & 63;
#pragma unroll
    for (int a = 0; a < AM; a++) {
        float mn = vals[a];
        float rf = (c == la[a0 + a]) ? vals[a] : 0.f;
        for (int off = 32; off; off >>= 1) {
            mn = fminf(mn, __shfl_xor(mn, off));
            rf += __shfl_xor(rf, off);
        }
        if (lane == 0) { s_min[wid][a] = mn; s_ref[wid][a] = rf; }
    }
    __syncthreads();
    if (tid < AM) {
        int a = tid;
        float mn = s_min[0][a], rf = s_ref[0][a];
#pragma unroll
        for (int w = 1; w < 16; w++) { mn = fminf(mn, s_min[w][a]); rf += s_ref[w][a]; }
        float v = fmaxf(rf - mn, 0.f);
        for (int off = 8; off; off >>= 1) v += __shfl_down(v, off);
        if (tid == 0) out_part[blockIdx.x] = v;
    }
}

// Final: sum all partials, combine.
__global__ __launch_bounds__(1024) void final_kernel(
    const float* __restrict__ ce_part, const float* __restrict__ ctr_part,
    const float* __restrict__ tr_part, float* __restrict__ out)
{
    int tid = threadIdx.x;
    float ce = 0.f, ctr = 0.f, tr = 0.f;
    for (int j = tid; j < 3072; j += 1024) ce += ce_part[j];
    if (tid < 256) ctr = ctr_part[tid];
    tr = tr_part[tid];
    for (int off = 32; off; off >>= 1) {
        ce += __shfl_xor(ce, off);
        ctr += __shfl_xor(ctr, off);
        tr += __shfl_xor(tr, off);
    }
    __shared__ float s[3][16];
    int wid = tid >> 6, lane = tid & 63;
    if (lane == 0) { s[0][wid] = ce; s[1][wid] = ctr; s[2][wid] = tr; }
    __syncthreads();
    if (tid == 0) {
        float tce = 0.f, tctr = 0.f, ttr = 0.f;
#pragma unroll
        for (int w = 0; w < 16; w++) { tce += s[0][w]; tctr += s[1][w]; ttr += s[2][w]; }
        float lsm = tce / (3.f * BB);
        out[0] = lsm + 0.1f * tctr + 1.0f * ttr;   // loss_total
        out[1] = ttr;                               // loss_triplet
        out[2] = lsm;                               // loss_softmax
        out[3] = tctr;                              // loss_center
    }
}

extern "C" void kernel_launch(void* const* d_in, const int* in_sizes, int n_in,
                              void* d_out, int out_size, void* d_ws, size_t ws_size,
                              hipStream_t stream) {
    const float* anchor   = (const float*)d_in[0];
    const float* positive = (const float*)d_in[1];
    const float* negative = (const float*)d_in[2];
    const float* outputs  = (const float*)d_in[3];
    const int*   la       = (const int*)d_in[4];
    const int*   ln       = (const int*)d_in[5];
    const float* ex       = (const float*)d_in[6];
    float* out = (float*)d_out;
    float* ws  = (float*)d_ws;

    float* ETp      = ws + OFF_ETP;
    float* esq      = ws + OFF_ESQ;
    float* asq      = ws + OFF_ASQ;
    float* ce_part  = ws + OFF_CEP;
    float* ctr_part = ws + OFF_CTP;
    float* tr_part  = ws + OFF_TRP;

    hipLaunchKernelGGL(transpose_kernel, dim3(512),  dim3(256),  0, stream, ex, ETp);
    hipLaunchKernelGGL(esq_kernel,       dim3(256),  dim3(256),  0, stream, ex, esq);
    hipLaunchKernelGGL(ce_kernel,        dim3(3072), dim3(256),  0, stream, outputs, la, ln, ce_part);
    hipLaunchKernelGGL(triplet_kernel,   dim3(1024), dim3(256),  0, stream, anchor, positive, negative, tr_part, asq);
    hipLaunchKernelGGL(center_kernel,    dim3(256),  dim3(1024), 0, stream, ETp, anchor, asq, esq, la, ctr_part);
    hipLaunchKernelGGL(final_kernel,     dim3(1),    dim3(1024), 0, stream, ce_part, ctr_part, tr_part, out);
}

// Round 2
// 47.649 us; speedup vs baseline: 2.6450x; 2.6450x over previous
//
#include <hip/hip_runtime.h>
#include <math.h>

// Problem constants
#define BB 4096      // batch
#define DD 512       // feature dim
#define CC 1000      // num classes
#define CPAD 1024    // padded classes

typedef __attribute__((ext_vector_type(8))) short short8;
typedef __attribute__((ext_vector_type(4))) float f32x4;

// ---------------- ws layout (float slots) ----------------
// Abf  : 4096x512 bf16 = 1,048,576 float slots
// Ebf  : 1024x512 bf16 =   262,144
// esq  : 1024
// asq  : 4096
// dref : 4096
// pmin : 4096x16 = 65536
// ce_part : 3072
// tr_part : 1024
#define OFF_ABF  0
#define OFF_EBF  1048576
#define OFF_ESQ  1310720
#define OFF_ASQ  1311744
#define OFF_DREF 1315840
#define OFF_PMIN 1319936
#define OFF_CEP  1385472
#define OFF_TRP  1388544

__device__ __forceinline__ unsigned short f2bf(float x) {
    unsigned u = __float_as_uint(x);
    unsigned r = (u + 0x7FFFu + ((u >> 16) & 1u)) >> 16;   // RNE
    return (unsigned short)r;
}

// anchor f32 -> bf16, 8 elems/thread. 1024 blocks x 256.
__global__ void conv_a_kernel(const float* __restrict__ a, unsigned short* __restrict__ ab) {
    int t = blockIdx.x * 256 + threadIdx.x;
    const float4* src = (const float4*)(a + (size_t)t * 8);
    float4 v0 = src[0], v1 = src[1];
    union { unsigned short u[8]; uint4 q; } o;
    o.u[0]=f2bf(v0.x); o.u[1]=f2bf(v0.y); o.u[2]=f2bf(v0.z); o.u[3]=f2bf(v0.w);
    o.u[4]=f2bf(v1.x); o.u[5]=f2bf(v1.y); o.u[6]=f2bf(v1.z); o.u[7]=f2bf(v1.w);
    *(uint4*)(ab + (size_t)t * 8) = o.q;
}

// exemplars f32 -> bf16 padded to 1024 rows (zeros beyond 1000). 256 blocks x 256.
__global__ void conv_e_kernel(const float* __restrict__ e, unsigned short* __restrict__ eb) {
    int t = blockIdx.x * 256 + threadIdx.x;     // 8-elem group id; row = t/64
    int row = t >> 6;
    union { unsigned short u[8]; uint4 q; } o;
    if (row < CC) {
        const float4* src = (const float4*)(e + (size_t)t * 8);
        float4 v0 = src[0], v1 = src[1];
        o.u[0]=f2bf(v0.x); o.u[1]=f2bf(v0.y); o.u[2]=f2bf(v0.z); o.u[3]=f2bf(v0.w);
        o.u[4]=f2bf(v1.x); o.u[5]=f2bf(v1.y); o.u[6]=f2bf(v1.z); o.u[7]=f2bf(v1.w);
    } else {
        o.q = make_uint4(0, 0, 0, 0);
    }
    *(uint4*)(eb + (size_t)t * 8) = o.q;
}

// esq[c] = sum_d E[c][d]^2  (0 for padded classes). 256 blocks x 256.
__global__ void esq_kernel(const float* __restrict__ ex, float* __restrict__ esq) {
    int wid = threadIdx.x >> 6, lane = threadIdx.x & 63;
    int c = blockIdx.x * 4 + wid;               // c in [0,1024)
    float s = 0.f;
    if (c < CC) {
        const float4* row = (const float4*)(ex + (size_t)c * DD);
#pragma unroll
        for (int k = 0; k < 2; k++) {
            float4 v = row[lane + k * 64];
            s += v.x * v.x + v.y * v.y + v.z * v.z + v.w * v.w;
        }
        for (int off = 32; off; off >>= 1) s += __shfl_xor(s, off);
    }
    if (lane == 0) esq[c] = s;
}

// Cross-entropy: one wave per row of outputs [12288][1000]; block partial sums.
__global__ void ce_kernel(const float* __restrict__ outp,
                          const int* __restrict__ la, const int* __restrict__ ln,
                          float* __restrict__ part) {
    int wid = threadIdx.x >> 6, lane = threadIdx.x & 63;
    int r = blockIdx.x * 4 + wid;               // r in [0,12288)
    int label = (r < 2 * BB) ? la[r & (BB - 1)] : ln[r - 2 * BB];
    const float* row = outp + (size_t)r * CC;
    float v[16];
#pragma unroll
    for (int k = 0; k < 16; k++) {
        int j = lane + k * 64;
        v[k] = (j < CC) ? row[j] : -INFINITY;
    }
    float m = v[0];
#pragma unroll
    for (int k = 1; k < 16; k++) m = fmaxf(m, v[k]);
    for (int off = 32; off; off >>= 1) m = fmaxf(m, __shfl_xor(m, off));
    float s = 0.f, lv = 0.f;
#pragma unroll
    for (int k = 0; k < 16; k++) {
        int j = lane + k * 64;
        s += __expf(v[k] - m);
        lv += (j == label) ? v[k] : 0.f;
    }
    for (int off = 32; off; off >>= 1) {
        s += __shfl_xor(s, off);
        lv += __shfl_xor(lv, off);
    }
    __shared__ float ps[4];
    if (lane == 0) ps[wid] = -(lv - m - __logf(s));
    __syncthreads();
    if (threadIdx.x == 0) part[blockIdx.x] = ps[0] + ps[1] + ps[2] + ps[3];
}

// Triplet loss + anchor sq norms + EXACT fp32 d_ref (dist to labeled exemplar).
// One wave per anchor row. 1024 blocks x 256.
__global__ void triplet_kernel(const float* __restrict__ a, const float* __restrict__ p,
                               const float* __restrict__ n, const float* __restrict__ ex,
                               const int* __restrict__ la,
                               float* __restrict__ part, float* __restrict__ asq,
                               float* __restrict__ dref) {
    int wid = threadIdx.x >> 6, lane = threadIdx.x & 63;
    int i = blockIdx.x * 4 + wid;               // anchor row
    int label = la[i];
    const float4* ar = (const float4*)(a + (size_t)i * DD);
    const float4* pr = (const float4*)(p + (size_t)i * DD);
    const float4* nr = (const float4*)(n + (size_t)i * DD);
    const float4* er = (const float4*)(ex + (size_t)label * DD);
    float sa = 0.f, sp = 0.f, sn = 0.f, se = 0.f;
#pragma unroll
    for (int k = 0; k < 2; k++) {
        int j = lane + k * 64;
        float4 av = ar[j], pv = pr[j], nv = nr[j], ev = er[j];
        sa += av.x * av.x + av.y * av.y + av.z * av.z + av.w * av.w;
        float dx = av.x - pv.x, dy = av.y - pv.y, dz = av.z - pv.z, dw = av.w - pv.w;
        sp += dx * dx + dy * dy + dz * dz + dw * dw;
        dx = av.x - nv.x; dy = av.y - nv.y; dz = av.z - nv.z; dw = av.w - nv.w;
        sn += dx * dx + dy * dy + dz * dz + dw * dw;
        dx = av.x - ev.x; dy = av.y - ev.y; dz = av.z - ev.z; dw = av.w - ev.w;
        se += dx * dx + dy * dy + dz * dz + dw * dw;
    }
    for (int off = 32; off; off >>= 1) {
        sa += __shfl_xor(sa, off);
        sp += __shfl_xor(sp, off);
        sn += __shfl_xor(sn, off);
        se += __shfl_xor(se, off);
    }
    __shared__ float ps[4];
    if (lane == 0) {
        asq[i] = sa;
        dref[i] = sqrtf(se);
        ps[wid] = fmaxf(sqrtf(sp) - sqrtf(sn), 0.f);
    }
    __syncthreads();
    if (threadIdx.x == 0) part[blockIdx.x] = ps[0] + ps[1] + ps[2] + ps[3];
}

// ---------------- bf16 MFMA GEMM + fused distance/min epilogue ----------------
// C[m][n] = dot(anchor[m], ex[n]); tile 64x64, BK=64, 256 threads (4 waves 2x2).
// LDS layout [64 rows][64 bf16] with XOR-swizzle: LDS[r][c16] holds global
// col16 (c16 ^ (r&7)); staged via global_load_lds with pre-swizzled source
// (rule #21: linear dest + inverse-swz source + swz read).
#define GL2LDS(gsrc, ldst) __builtin_amdgcn_global_load_lds( \
    (const __attribute__((address_space(1))) unsigned int*)(gsrc), \
    (__attribute__((address_space(3))) unsigned int*)(ldst), 16, 0, 0)

__global__ __launch_bounds__(256) void gemm_min_kernel(
    const unsigned short* __restrict__ Ab, const unsigned short* __restrict__ Eb,
    const float* __restrict__ asq, const float* __restrict__ esq,
    float* __restrict__ pmin)
{
    __shared__ unsigned short lA[64 * 64];
    __shared__ unsigned short lB[64 * 64];
    __shared__ float s_pm[2][64];

    const int tid = threadIdx.x;
    const int w = tid >> 6, lane = tid & 63;
    const int wm = w >> 1, wn = w & 1;          // wave tile = 32x32 at (wm*32, wn*32)
    const int hi = lane >> 4, lo = lane & 15;
    const int lrow = lane >> 3, l8 = lane & 7;

    const int bm = blockIdx.x >> 4, bn = blockIdx.x & 15;   // 64 x 16 blocks
    const int gm0 = bm * 64, gn0 = bn * 64;

    f32x4 acc[2][2];
#pragma unroll
    for (int mi = 0; mi < 2; mi++)
#pragma unroll
        for (int ni = 0; ni < 2; ni++) acc[mi][ni] = (f32x4){0.f, 0.f, 0.f, 0.f};

    for (int kt = 0; kt < DD / 64; kt++) {
        // ---- stage A,B tiles (each wave: rows w*16 .. w*16+15 of each) ----
#pragma unroll
        for (int i = 0; i < 2; i++) {
            int r0 = w * 16 + i * 8;
            int row = r0 + lrow;
            int c16 = l8 ^ (row & 7);
            GL2LDS(Ab + ((size_t)(gm0 + row) << 9) + kt * 64 + (c16 << 3), &lA[r0 * 64]);
            GL2LDS(Eb + ((size_t)(gn0 + row) << 9) + kt * 64 + (c16 << 3), &lB[r0 * 64]);
        }
        asm volatile("s_waitcnt vmcnt(0)" ::: "memory");
        __syncthreads();

        // ---- compute: 2 K=32 sub-steps, 4 mfma each ----
#pragma unroll
        for (int kk = 0; kk < 2; kk++) {
            int g16 = kk * 4 + hi;
            int rA0 = wm * 32 + lo,      rA1 = wm * 32 + 16 + lo;
            int rB0 = wn * 32 + lo,      rB1 = wn * 32 + 16 + lo;
            short8 a0 = *(const short8*)&lA[rA0 * 64 + ((g16 ^ (rA0 & 7)) << 3)];
            short8 a1 = *(const short8*)&lA[rA1 * 64 + ((g16 ^ (rA1 & 7)) << 3)];
            short8 b0 = *(const short8*)&lB[rB0 * 64 + ((g16 ^ (rB0 & 7)) << 3)];
            short8 b1 = *(const short8*)&lB[rB1 * 64 + ((g16 ^ (rB1 & 7)) << 3)];
            acc[0][0] = __builtin_amdgcn_mfma_f32_16x16x32_bf16(a0, b0, acc[0][0], 0, 0, 0);
            acc[0][1] = __builtin_amdgcn_mfma_f32_16x16x32_bf16(a0, b1, acc[0][1], 0, 0, 0);
            acc[1][0] = __builtin_amdgcn_mfma_f32_16x16x32_bf16(a1, b0, acc[1][0], 0, 0, 0);
            acc[1][1] = __builtin_amdgcn_mfma_f32_16x16x32_bf16(a1, b1, acc[1][1], 0, 0, 0);
        }
        __syncthreads();
    }

    // ---- epilogue: d = sqrt(asq + esq - 2 dot), min over this block's 64 cols ----
    // C/D layout: col = lane&15 (n), row = (lane>>4)*4 + j (m)  [m89-verified]
    float aq[2][4];
    {
        float4 a0 = *(const float4*)&asq[gm0 + wm * 32 + hi * 4];
        float4 a1 = *(const float4*)&asq[gm0 + wm * 32 + 16 + hi * 4];
        aq[0][0]=a0.x; aq[0][1]=a0.y; aq[0][2]=a0.z; aq[0][3]=a0.w;
        aq[1][0]=a1.x; aq[1][1]=a1.y; aq[1][2]=a1.z; aq[1][3]=a1.w;
    }
    float esqc[2]; int bad[2];
#pragma unroll
    for (int ni = 0; ni < 2; ni++) {
        int gn = gn0 + wn * 32 + ni * 16 + lo;
        esqc[ni] = esq[gn];
        bad[ni] = (gn >= CC);
    }
    float vmin[2][4];
#pragma unroll
    for (int mi = 0; mi < 2; mi++)
#pragma unroll
        for (int j = 0; j < 4; j++) {
            float best = INFINITY;
#pragma unroll
            for (int ni = 0; ni < 2; ni++) {
                float d2 = aq[mi][j] + esqc[ni] - 2.f * acc[mi][ni][j];
                float d = sqrtf(fmaxf(d2, 0.f));
                if (bad[ni]) d = INFINITY;
                best = fminf(best, d);
            }
            vmin[mi][j] = best;
        }
#pragma unroll
    for (int off = 1; off < 16; off <<= 1)
#pragma unroll
        for (int mi = 0; mi < 2; mi++)
#pragma unroll
            for (int j = 0; j < 4; j++)
                vmin[mi][j] = fminf(vmin[mi][j], __shfl_xor(vmin[mi][j], off));

    if (lo == 0) {
#pragma unroll
        for (int mi = 0; mi < 2; mi++)
#pragma unroll
            for (int j = 0; j < 4; j++)
                s_pm[wn][wm * 32 + mi * 16 + hi * 4 + j] = vmin[mi][j];
    }
    __syncthreads();
    if (tid < 64) {
        float m2 = fminf(s_pm[0][tid], s_pm[1][tid]);
        pmin[(size_t)(gm0 + tid) * 16 + bn] = m2;
    }
}

// Final: sum partials; center loss from pmin + dref; combine.
__global__ __launch_bounds__(1024) void final_kernel(
    const float* __restrict__ ce_part, const float* __restrict__ tr_part,
    const float* __restrict__ pmin, const float* __restrict__ dref,
    float* __restrict__ out)
{
    int tid = threadIdx.x;
    float ce = 0.f, tr = tr_part[tid], ctr = 0.f;
#pragma unroll
    for (int j = 0; j < 3; j++) ce += ce_part[tid + j * 1024];
#pragma unroll
    for (int a = 0; a < 4; a++) {
        int m = a * 1024 + tid;
        const float4* pr = (const float4*)(pmin + (size_t)m * 16);
        float4 p0 = pr[0], p1 = pr[1], p2 = pr[2], p3 = pr[3];
        float mn = fminf(fminf(fminf(p0.x, p0.y), fminf(p0.z, p0.w)),
                         fminf(fminf(p1.x, p1.y), fminf(p1.z, p1.w)));
        mn = fminf(mn, fminf(fminf(fminf(p2.x, p2.y), fminf(p2.z, p2.w)),
                             fminf(fminf(p3.x, p3.y), fminf(p3.z, p3.w))));
        ctr += fmaxf(dref[m] - mn, 0.f);
    }
    for (int off = 32; off; off >>= 1) {
        ce += __shfl_xor(ce, off);
        tr += __shfl_xor(tr, off);
        ctr += __shfl_xor(ctr, off);
    }
    __shared__ float s[3][16];
    int wid = tid >> 6, lane = tid & 63;
    if (lane == 0) { s[0][wid] = ce; s[1][wid] = tr; s[2][wid] = ctr; }
    __syncthreads();
    if (tid == 0) {
        float tce = 0.f, ttr = 0.f, tctr = 0.f;
#pragma unroll
        for (int w = 0; w < 16; w++) { tce += s[0][w]; ttr += s[1][w]; tctr += s[2][w]; }
        float lsm = tce / (3.f * BB);
        out[0] = lsm + 0.1f * tctr + 1.0f * ttr;
        out[1] = ttr;
        out[2] = lsm;
        out[3] = tctr;
    }
}

extern "C" void kernel_launch(void* const* d_in, const int* in_sizes, int n_in,
                              void* d_out, int out_size, void* d_ws, size_t ws_size,
                              hipStream_t stream) {
    const float* anchor   = (const float*)d_in[0];
    const float* positive = (const float*)d_in[1];
    const float* negative = (const float*)d_in[2];
    const float* outputs  = (const float*)d_in[3];
    const int*   la       = (const int*)d_in[4];
    const int*   ln       = (const int*)d_in[5];
    const float* ex       = (const float*)d_in[6];
    float* out = (float*)d_out;
    float* ws  = (float*)d_ws;

    unsigned short* Abf = (unsigned short*)(ws + OFF_ABF);
    unsigned short* Ebf = (unsigned short*)(ws + OFF_EBF);
    float* esq      = ws + OFF_ESQ;
    float* asq      = ws + OFF_ASQ;
    float* dref     = ws + OFF_DREF;
    float* pmin     = ws + OFF_PMIN;
    float* ce_part  = ws + OFF_CEP;
    float* tr_part  = ws + OFF_TRP;

    hipLaunchKernelGGL(conv_a_kernel,   dim3(1024), dim3(256),  0, stream, anchor, Abf);
    hipLaunchKernelGGL(conv_e_kernel,   dim3(256),  dim3(256),  0, stream, ex, Ebf);
    hipLaunchKernelGGL(esq_kernel,      dim3(256),  dim3(256),  0, stream, ex, esq);
    hipLaunchKernelGGL(ce_kernel,       dim3(3072), dim3(256),  0, stream, outputs, la, ln, ce_part);
    hipLaunchKernelGGL(triplet_kernel,  dim3(1024), dim3(256),  0, stream, anchor, positive, negative, ex, la, tr_part, asq, dref);
    hipLaunchKernelGGL(gemm_min_kernel, dim3(1024), dim3(256),  0, stream, Abf, Ebf, asq, esq, pmin);
    hipLaunchKernelGGL(final_kernel,    dim3(1),    dim3(1024), 0, stream, ce_part, tr_part, pmin, dref, out);
}